// Round 10
// baseline (185.194 us; speedup 1.0000x reference)
//
#include <hip/hip_runtime.h>
#include <cstdint>
#include <cstddef>

// Block-diagonal GRU on MI355X (gfx950), fully fused bf16 MFMA path.
// B=8192, IN=1024, H=2048, NB=8, BS=256, 3H=6144.
// Round 10: B operands (W_ir strips / W_h) bypass LDS entirely — loaded
// global->register from a FRAGMENT-MAJOR bf16 image produced by the cast
// kernel (frag[row16][k32][lane][8] => each B load is one coalesced 1KB
// segment at base+lane*16B, L2-resident). LDS carries only A (32 KiB,
// 2-slot dbuf): per-CU LDS traffic drops 240KB -> 96KB per K-tile-pair,
// breaking the LDS-port wall that capped rounds 4-9 at ~140us.

typedef __attribute__((ext_vector_type(8))) short bf16x8;
typedef __attribute__((ext_vector_type(4))) float f32x4;

__device__ __forceinline__ unsigned short f2bf(float f) {
    uint32_t u = __float_as_uint(f);
    u += 0x7FFFu + ((u >> 16) & 1u);   // round-to-nearest-even
    return (unsigned short)(u >> 16);
}
__device__ __forceinline__ float bf2f(unsigned short b) {
    return __uint_as_float(((uint32_t)b) << 16);
}

__device__ __forceinline__ void gload16(const void* g, void* l) {
    __builtin_amdgcn_global_load_lds(
        (const __attribute__((address_space(1))) void*)g,
        (__attribute__((address_space(3))) void*)l,
        16, 0, 0);
}

__device__ __forceinline__ float sigmoidf_(float x) {
    return 1.0f / (1.0f + __expf(-x));
}
__device__ __forceinline__ float tanhf_(float x) {
    float e = __expf(-2.0f * fabsf(x));
    float t = (1.0f - e) / (1.0f + e);
    return copysignf(t, x);
}

// ---------------------------------------------------------------- cast
// Region map (256-thr blocks, all boundaries multiples of 256):
//  t in [0, 2097152)                 : x float4 cast (linear)
//  t in [2097152, 6291456)           : h float4 cast (linear)
//  t in [6291456, 7077888)           : W_ir -> fragment-major bf16
//  t in [7077888, 7274496)           : W_h  -> fragment-major bf16
// W_ir frag unit u: lane=u&63, fi=u>>6, kblk=fi&31, rb=fi>>5.
//   reads W_ir[rb*16 + (lane&15)][kblk*32 + (lane>>4)*8 .. +8] (8 f32)
//   writes 8 bf16 at out[u*8].
// W_h frag unit u2: lane=u2&63, fi=u2>>6, kb=fi/384, rem=fi%384
//   (rem = rb2*8 + kblk2, rb2<48, kblk2<8);
//   reads W_h[kb][rb2*16 + (lane&15)][kblk2*32 + (lane>>4)*8 .. +8]
__global__ __launch_bounds__(256)
void cast_all(const float* __restrict__ x, const float* __restrict__ wir,
              const float* __restrict__ h, const float* __restrict__ wh,
              unsigned short* __restrict__ xb, unsigned short* __restrict__ wirF,
              unsigned short* __restrict__ hb, unsigned short* __restrict__ whF) {
    const int t = blockIdx.x * 256 + threadIdx.x;
    if (t < 6291456) {   // linear casts
        const float* s; unsigned short* d; int j;
        if (t < 2097152) { s = x; d = xb; j = t; }
        else             { s = h; d = hb; j = t - 2097152; }
        const float4 v = *reinterpret_cast<const float4*>(s + (size_t)j * 4);
        ushort4 o;
        o.x = f2bf(v.x); o.y = f2bf(v.y); o.z = f2bf(v.z); o.w = f2bf(v.w);
        *reinterpret_cast<ushort4*>(d + (size_t)j * 4) = o;
        return;
    }
    const float* src; unsigned short* dst; size_t in_off; int u;
    if (t < 7077888) {   // W_ir fragments
        u = t - 6291456;
        const int lane = u & 63, fi = u >> 6;
        const int kblk = fi & 31, rb = fi >> 5;
        in_off = (size_t)(rb * 16 + (lane & 15)) * 1024 + kblk * 32 + (lane >> 4) * 8;
        src = wir; dst = wirF;
    } else {             // W_h fragments
        u = t - 7077888;
        const int lane = u & 63, fi = u >> 6;
        const int kb = fi / 384, rem = fi - kb * 384;
        const int rb2 = rem >> 3, kblk2 = rem & 7;
        in_off = (size_t)kb * 196608
               + (size_t)(rb2 * 16 + (lane & 15)) * 256 + kblk2 * 32 + (lane >> 4) * 8;
        src = wh; dst = whF;
    }
    const float4 v0 = *reinterpret_cast<const float4*>(src + in_off);
    const float4 v1 = *reinterpret_cast<const float4*>(src + in_off + 4);
    bf16x8 o;
    o[0] = (short)f2bf(v0.x); o[1] = (short)f2bf(v0.y);
    o[2] = (short)f2bf(v0.z); o[3] = (short)f2bf(v0.w);
    o[4] = (short)f2bf(v1.x); o[5] = (short)f2bf(v1.y);
    o[6] = (short)f2bf(v1.z); o[7] = (short)f2bf(v1.w);
    *reinterpret_cast<bf16x8*>(dst + (size_t)u * 8) = o;
}

// ---------------------------------------------------------------- fused GRU
// 256 thr (4 waves 2Mx2N), BM=128, 64 h-cols, 3 strips, BK=64, 20 K-tiles.
// acc groups: 0=r(sum), 1=z(sum), 2=wxn, 3=whn. NT = 2 (phase1) / 3 (phase2).
// A through LDS (2 x 16KB slots, T2-swizzled); B direct from frag image.

#define MFMA_(a_, b_, c_) __builtin_amdgcn_mfma_f32_16x16x32_bf16(a_, b_, c_, 0, 0, 0)

#define MM24(AV, KH, NT) do {                                                  \
    _Pragma("unroll")                                                          \
    for (int m_ = 0; m_ < 4; ++m_) {                                           \
        acc[0][m_][0]  = MFMA_(AV[m_], bv[0][0][KH], acc[0][m_][0]);           \
        acc[0][m_][1]  = MFMA_(AV[m_], bv[0][1][KH], acc[0][m_][1]);           \
        acc[1][m_][0]  = MFMA_(AV[m_], bv[1][0][KH], acc[1][m_][0]);           \
        acc[1][m_][1]  = MFMA_(AV[m_], bv[1][1][KH], acc[1][m_][1]);           \
        acc[NT][m_][0] = MFMA_(AV[m_], bv[2][0][KH], acc[NT][m_][0]);          \
        acc[NT][m_][1] = MFMA_(AV[m_], bv[2][1][KH], acc[NT][m_][1]);          \
    }                                                                          \
} while (0)

// B fragment loads, phase1: frag offset ((s*128 + rbB1 + n)*32 + kt*2 + kh)*512
#define BL1(kt) do {                                                           \
    _Pragma("unroll") for (int s_ = 0; s_ < 3; ++s_)                           \
    _Pragma("unroll") for (int n_ = 0; n_ < 2; ++n_)                           \
    _Pragma("unroll") for (int kh_ = 0; kh_ < 2; ++kh_)                        \
        bv[s_][n_][kh_] = *(const bf16x8*)(WirF +                              \
            (((size_t)(s_ * 128 + rbB1 + n_) * 32 + (kt) * 2 + kh_) << 9) + l8); \
} while (0)
// phase2: base kb*196608 + ((s*16 + rbB2 + n)*8 + k2*2 + kh)*512
#define BL2(k2) do {                                                           \
    _Pragma("unroll") for (int s_ = 0; s_ < 3; ++s_)                           \
    _Pragma("unroll") for (int n_ = 0; n_ < 2; ++n_)                           \
    _Pragma("unroll") for (int kh_ = 0; kh_ < 2; ++kh_)                        \
        bv[s_][n_][kh_] = *(const bf16x8*)(WhF + whbase +                      \
            (((size_t)(s_ * 16 + rbB2 + n_) * 8 + (k2) * 2 + kh_) << 9) + l8); \
} while (0)

// A staging (4 x gload16; inverse-swizzled source, linear LDS dest)
#define I_A1(kt, ds) do {                                                      \
    gload16(XbB + 0 * 32768 + (kt) * 64, As + (ds) * 8192 + 0 * 2048 + doff);  \
    gload16(XbB + 1 * 32768 + (kt) * 64, As + (ds) * 8192 + 1 * 2048 + doff);  \
    gload16(XbB + 2 * 32768 + (kt) * 64, As + (ds) * 8192 + 2 * 2048 + doff);  \
    gload16(XbB + 3 * 32768 + (kt) * 64, As + (ds) * 8192 + 3 * 2048 + doff); } while (0)
#define I_A2(k2, ds) do {                                                      \
    gload16(XhB + 0 * 65536 + (k2) * 64, As + (ds) * 8192 + 0 * 2048 + doff);  \
    gload16(XhB + 1 * 65536 + (k2) * 64, As + (ds) * 8192 + 1 * 2048 + doff);  \
    gload16(XhB + 2 * 65536 + (k2) * 64, As + (ds) * 8192 + 2 * 2048 + doff);  \
    gload16(XhB + 3 * 65536 + (k2) * 64, As + (ds) * 8192 + 3 * 2048 + doff); } while (0)

// Body for K-tile t (slot sl = t&1):
//  12 B-loads (global->reg) ; vmcnt(12) => A(t) staging (4 older DMAs) done ;
//  barrier (A(t) visible, slot nxt readers done) ; A-stage(t+1 -> nxt) ;
//  8 ds_read A ; 48 MFMA (compiler inserts counted lgkm/vm waits for uses).
#define BODY(sl, BL, AST, NT) do {                                             \
    BL;                                                                        \
    asm volatile("s_waitcnt vmcnt(12)" ::: "memory");                          \
    __builtin_amdgcn_s_barrier();                                              \
    AST;                                                                       \
    const unsigned short* aS = As + (sl) * 8192;                               \
    _Pragma("unroll") for (int m_ = 0; m_ < 4; ++m_)                           \
        av0[m_] = *(const bf16x8*)(aS + (wm * 64 + m_ * 16 + fr) * 64 + kb0);  \
    _Pragma("unroll") for (int m_ = 0; m_ < 4; ++m_)                           \
        av1[m_] = *(const bf16x8*)(aS + (wm * 64 + m_ * 16 + fr) * 64 + kb1);  \
    MM24(av0, 0, NT);                                                          \
    MM24(av1, 1, NT);                                                          \
} while (0)

__global__ __launch_bounds__(256, 2)
void gru_fused(const unsigned short* __restrict__ Xb,    // [8192][1024] bf16
               const unsigned short* __restrict__ WirF,  // frag-major W_ir bf16
               const unsigned short* __restrict__ Hbb,   // [8192][2048] bf16
               const unsigned short* __restrict__ WhF,   // frag-major W_h bf16
               const float* __restrict__ b_ir_lin,       // [6144]
               const float* __restrict__ b_ir,           // [6144]
               const float* __restrict__ b_hr,           // [6144]
               float* __restrict__ out) {                // [8192][2048] f32
    constexpr int K1 = 1024, H = 2048;
    __shared__ unsigned short lds[2 * 8192];   // 32 KiB, A only
    unsigned short* const As = lds;

    const int tid  = threadIdx.x;
    const int lane = tid & 63;
    const int w    = tid >> 6;   // 0..3
    const int wm   = w >> 1;     // 0..1 (64-row half)
    const int wn   = w & 1;      // 0..1 (32-col half)

    // Grid: 2048 = 8 kb (XCD-exclusive) x 64 bm x 4 hsub (hsub innermost).
    const int bid  = blockIdx.x;
    const int kb   = bid & 7;
    const int idx  = bid >> 3;
    const int bm   = (idx >> 2) * 128;
    const int hsub = idx & 3;
    const int hcb  = kb * 256 + hsub * 64;   // h-column base

    // ---- A staging bases (inverse-swizzled global, linear LDS dest, T2/G21)
    const int srow  = tid >> 3;                 // 0..31
    const int chunk = (tid & 7) ^ (srow & 7);   // XOR involution
    const int scol  = chunk * 8;
    const int doff  = tid * 8;
    const unsigned short* XbB = Xb  + (size_t)(bm + srow) * K1 + scol;
    const unsigned short* XhB = Hbb + (size_t)(bm + srow) * H + kb * 256 + scol;

    // ---- A fragment read offsets (swizzled, rows 128 B)
    const int fr  = lane & 15;
    const int k0e = (lane >> 4) * 8;
    const int mfr = (fr & 7) << 4;
    const int kb0 = ((k0e * 2) ^ mfr) >> 1;
    const int kb1 = (((k0e * 2) + 64) ^ mfr) >> 1;

    // ---- B fragment addressing (direct global, frag-major image)
    const int l8   = lane * 8;
    const int rbB1 = kb * 16 + hsub * 4 + wn * 2;   // + s*128 + n
    const int rbB2 = hsub * 4 + wn * 2;             // + s*16 + n
    const size_t whbase = (size_t)kb * 196608;

    f32x4 acc[4][4][2] = {};   // [group][m-frag][n-frag]
    bf16x8 av0[4], av1[4], bv[3][2][2];

    // ---- prologue: stage A tile 0 into slot 0
    I_A1(0, 0);
    asm volatile("s_waitcnt vmcnt(0)" ::: "memory");
    __builtin_amdgcn_s_barrier();

    // ---- phase1: tiles 0..14
    BODY(0, BL1(0),  I_A1(1, 1),  2);
    BODY(1, BL1(1),  I_A1(2, 0),  2);
    BODY(0, BL1(2),  I_A1(3, 1),  2);
    BODY(1, BL1(3),  I_A1(4, 0),  2);
    BODY(0, BL1(4),  I_A1(5, 1),  2);
    BODY(1, BL1(5),  I_A1(6, 0),  2);
    BODY(0, BL1(6),  I_A1(7, 1),  2);
    BODY(1, BL1(7),  I_A1(8, 0),  2);
    BODY(0, BL1(8),  I_A1(9, 1),  2);
    BODY(1, BL1(9),  I_A1(10, 0), 2);
    BODY(0, BL1(10), I_A1(11, 1), 2);
    BODY(1, BL1(11), I_A1(12, 0), 2);
    BODY(0, BL1(12), I_A1(13, 1), 2);
    BODY(1, BL1(13), I_A1(14, 0), 2);
    BODY(0, BL1(14), I_A1(15, 1), 2);
    // ---- tile 15 (last phase1), stage first phase2 A-tile
    BODY(1, BL1(15), I_A2(0, 0),  2);
    // ---- phase2: tiles 16..19
    BODY(0, BL2(0),  I_A2(1, 1),  3);
    BODY(1, BL2(1),  I_A2(2, 0),  3);
    BODY(0, BL2(2),  I_A2(3, 1),  3);
    BODY(1, BL2(3),  ((void)0),   3);

    // ---- gate epilogue (h read as bf16)
    const int rq = (lane >> 4) * 4;
    #pragma unroll
    for (int n = 0; n < 2; ++n) {
        const int hcol = hcb + wn * 32 + n * 16 + fr;   // 0..2047
        const int lcol = hcol & 255;                    // within diagonal block
        const float bir0 = b_ir_lin[hcol]        + b_ir[hcol];
        const float bir1 = b_ir_lin[2048 + hcol] + b_ir[2048 + hcol];
        const float bir2 = b_ir_lin[4096 + hcol] + b_ir[4096 + hcol];
        const float bhr0 = b_hr[kb * 768 + lcol];
        const float bhr1 = b_hr[kb * 768 + 256 + lcol];
        const float bhr2 = b_hr[kb * 768 + 512 + lcol];
        #pragma unroll
        for (int mi = 0; mi < 4; ++mi) {
            #pragma unroll
            for (int r = 0; r < 4; ++r) {
                const int row = bm + wm * 64 + mi * 16 + rq + r;
                const float pr = acc[0][mi][n][r] + bir0 + bhr0;
                const float pz = acc[1][mi][n][r] + bir1 + bhr1;
                const float xn = acc[2][mi][n][r] + bir2;
                const float hn = acc[3][mi][n][r] + bhr2;
                const float rg = sigmoidf_(pr);
                const float zg = sigmoidf_(pz);
                const float ng = tanhf_(xn + rg * hn);
                const float hv = bf2f(Hbb[(size_t)row * H + hcol]);
                out[(size_t)row * H + hcol] = (1.0f - zg) * hv + zg * ng;
            }
        }
    }
}

// ---------------------------------------------------------------- launch
extern "C" void kernel_launch(void* const* d_in, const int* in_sizes, int n_in,
                              void* d_out, int out_size, void* d_ws, size_t ws_size,
                              hipStream_t stream) {
    const float* x        = (const float*)d_in[0];
    const float* h        = (const float*)d_in[1];
    const float* W_ir     = (const float*)d_in[2];
    const float* b_ir_lin = (const float*)d_in[3];
    const float* b_ir     = (const float*)d_in[4];
    const float* W_h      = (const float*)d_in[5];
    const float* b_hr     = (const float*)d_in[6];
    float* out = (float*)d_out;

    char* ws = (char*)d_ws;
    unsigned short* xb   = (unsigned short*)(ws);               // 16 MiB
    unsigned short* wirF = (unsigned short*)(ws + 16777216);    // 12 MiB (frag-major)
    unsigned short* hb   = (unsigned short*)(ws + 29360128);    // 32 MiB
    unsigned short* whF  = (unsigned short*)(ws + 62914560);    //  3 MiB (frag-major)

    cast_all<<<28416, 256, 0, stream>>>(x, W_ir, h, W_h, xb, wirF, hb, whF);

    gru_fused<<<2048, 256, 0, stream>>>(xb, wirF, hb, whF,
                                        b_ir_lin, b_ir, b_hr, out);
}

// Round 11
// 181.076 us; speedup vs baseline: 1.0227x; 1.0227x over previous
//
#include <hip/hip_runtime.h>
#include <cstdint>
#include <cstddef>

// Block-diagonal GRU on MI355X (gfx950), fully fused bf16 MFMA path.
// B=8192, IN=1024, H=2048, NB=8, BS=256, 3H=6144.
// Round 11: BM=256 block (512 thr, 8 waves 2Mx4N; wave = 128 rows x 16
// h-cols x 3 strips, acc[4][8]). 3-slot A (96KB) + 2-slot B (48KB) LDS
// pipeline, counted vmcnt(4) per K-tile (never 0 until the last tile),
// ONE barrier per K-tile, no explicit lgkm drains (compiler counted waits).
// Staging bytes/FLOP 1.4x better than the 128-row block; sync density 1/5th
// of rounds 4-9; A prefetch depth 2 K-tiles, B depth 1.

typedef __attribute__((ext_vector_type(8))) short bf16x8;
typedef __attribute__((ext_vector_type(4))) float f32x4;

__device__ __forceinline__ unsigned short f2bf(float f) {
    uint32_t u = __float_as_uint(f);
    u += 0x7FFFu + ((u >> 16) & 1u);   // round-to-nearest-even
    return (unsigned short)(u >> 16);
}
__device__ __forceinline__ float bf2f(unsigned short b) {
    return __uint_as_float(((uint32_t)b) << 16);
}

__device__ __forceinline__ void gload16(const void* g, void* l) {
    __builtin_amdgcn_global_load_lds(
        (const __attribute__((address_space(1))) void*)g,
        (__attribute__((address_space(3))) void*)l,
        16, 0, 0);
}

__device__ __forceinline__ float sigmoidf_(float x) {
    return 1.0f / (1.0f + __expf(-x));
}
__device__ __forceinline__ float tanhf_(float x) {
    float e = __expf(-2.0f * fabsf(x));
    float t = (1.0f - e) / (1.0f + e);
    return copysignf(t, x);
}

// ---------------------------------------------------------------- one cast
// regions (in float4 units): x 2097152 | W_ir 1572864 | h 4194304 | W_h 393216
__global__ __launch_bounds__(256)
void cast_all(const float* __restrict__ x, const float* __restrict__ wir,
              const float* __restrict__ h, const float* __restrict__ wh,
              unsigned short* __restrict__ xb, unsigned short* __restrict__ wirb,
              unsigned short* __restrict__ hb, unsigned short* __restrict__ whb) {
    const int i = blockIdx.x * 256 + threadIdx.x;
    const float* s; unsigned short* d; int j;
    if (i < 2097152)      { s = x;   d = xb;   j = i; }
    else if (i < 3670016) { s = wir; d = wirb; j = i - 2097152; }
    else if (i < 7864320) { s = h;   d = hb;   j = i - 3670016; }
    else                  { s = wh;  d = whb;  j = i - 7864320; }
    const float4 v = *reinterpret_cast<const float4*>(s + (size_t)j * 4);
    ushort4 o;
    o.x = f2bf(v.x); o.y = f2bf(v.y); o.z = f2bf(v.z); o.w = f2bf(v.w);
    *reinterpret_cast<ushort4*>(d + (size_t)j * 4) = o;
}

// ---------------------------------------------------------------- fused GRU
// acc groups: 0=r(sum), 1=z(sum), 2=wxn, 3=whn. NT = 2 (phase1) / 3 (phase2).
// A tile 256x64 (4 x 64-row groups), B tile 192x64 (3 strip groups).
// Per thread per K-tile: 3 B-gloads + 4 A-gloads. T2 XOR swizzle via
// inverse-swizzled global source + swizzled ds_read (G21).

#define MM24(KH, NT) do {                                                      \
    _Pragma("unroll")                                                          \
    for (int m_ = 0; m_ < 8; ++m_) {                                           \
        acc[0][m_]  = __builtin_amdgcn_mfma_f32_16x16x32_bf16(                 \
            av[m_], bv[0][KH], acc[0][m_], 0, 0, 0);                           \
        acc[1][m_]  = __builtin_amdgcn_mfma_f32_16x16x32_bf16(                 \
            av[m_], bv[1][KH], acc[1][m_], 0, 0, 0);                           \
        acc[NT][m_] = __builtin_amdgcn_mfma_f32_16x16x32_bf16(                 \
            av[m_], bv[2][KH], acc[NT][m_], 0, 0, 0);                          \
    }                                                                          \
} while (0)

// stage macros: per thread, dest = slot base + group*4096 + tid*8
#define SB1(kt, ds) do {                                                       \
    gload16(WirB + 0 * 2097152 + (kt) * 64, Bs + (ds) * 12288 + 0 * 4096 + doff); \
    gload16(WirB + 1 * 2097152 + (kt) * 64, Bs + (ds) * 12288 + 1 * 4096 + doff); \
    gload16(WirB + 2 * 2097152 + (kt) * 64, Bs + (ds) * 12288 + 2 * 4096 + doff); \
} while (0)
#define SA1(kt, ds) do {                                                       \
    gload16(XbB + 0 * 65536 + (kt) * 64, As + (ds) * 16384 + 0 * 4096 + doff); \
    gload16(XbB + 1 * 65536 + (kt) * 64, As + (ds) * 16384 + 1 * 4096 + doff); \
    gload16(XbB + 2 * 65536 + (kt) * 64, As + (ds) * 16384 + 2 * 4096 + doff); \
    gload16(XbB + 3 * 65536 + (kt) * 64, As + (ds) * 16384 + 3 * 4096 + doff); \
} while (0)
#define SB2(k2, ds) do {                                                       \
    gload16(WhB + 0 * 65536 + (k2) * 64, Bs + (ds) * 12288 + 0 * 4096 + doff); \
    gload16(WhB + 1 * 65536 + (k2) * 64, Bs + (ds) * 12288 + 1 * 4096 + doff); \
    gload16(WhB + 2 * 65536 + (k2) * 64, Bs + (ds) * 12288 + 2 * 4096 + doff); \
} while (0)
#define SA2(k2, ds) do {                                                       \
    gload16(XhB + 0 * 131072 + (k2) * 64, As + (ds) * 16384 + 0 * 4096 + doff); \
    gload16(XhB + 1 * 131072 + (k2) * 64, As + (ds) * 16384 + 1 * 4096 + doff); \
    gload16(XhB + 2 * 131072 + (k2) * 64, As + (ds) * 16384 + 2 * 4096 + doff); \
    gload16(XhB + 3 * 131072 + (k2) * 64, As + (ds) * 16384 + 3 * 4096 + doff); \
} while (0)
#define SNOP ((void)0)

// Body for K-tile t: wait (counted) | barrier | stage B(t+1), A(t+2) |
// 22 ds_read + 48 MFMA, compiler-scheduled (counted lgkm waits).
#define KBODY(sa, sb, WT, STB, STA, NT) do {                                   \
    asm volatile("s_waitcnt vmcnt(" WT ")" ::: "memory");                      \
    __builtin_amdgcn_s_barrier();                                              \
    STB;                                                                       \
    STA;                                                                       \
    const unsigned short* aS = As + (sa) * 16384;                              \
    const unsigned short* bS = Bs + (sb) * 12288;                              \
    _Pragma("unroll")                                                          \
    for (int m_ = 0; m_ < 8; ++m_)                                             \
        av[m_] = *(const bf16x8*)(aS + (wm * 128 + m_ * 16 + fr) * 64 + kb0);  \
    _Pragma("unroll")                                                          \
    for (int s_ = 0; s_ < 3; ++s_) {                                           \
        bv[s_][0] = *(const bf16x8*)(bS + (s_ * 64 + wn * 16 + fr) * 64 + kb0);\
        bv[s_][1] = *(const bf16x8*)(bS + (s_ * 64 + wn * 16 + fr) * 64 + kb1);\
    }                                                                          \
    MM24(0, NT);                                                               \
    _Pragma("unroll")                                                          \
    for (int m_ = 0; m_ < 8; ++m_)                                             \
        av[m_] = *(const bf16x8*)(aS + (wm * 128 + m_ * 16 + fr) * 64 + kb1);  \
    MM24(1, NT);                                                               \
} while (0)

__global__ __launch_bounds__(512, 2)
void gru_fused(const unsigned short* __restrict__ Xb,    // [8192][1024] bf16
               const unsigned short* __restrict__ Wirb,  // [6144][1024] bf16
               const unsigned short* __restrict__ Hbb,   // [8192][2048] bf16
               const unsigned short* __restrict__ Whb,   // [8][768][256] bf16
               const float* __restrict__ b_ir_lin,       // [6144]
               const float* __restrict__ b_ir,           // [6144]
               const float* __restrict__ b_hr,           // [6144]
               float* __restrict__ out) {                // [8192][2048] f32
    constexpr int K1 = 1024, H = 2048;
    __shared__ unsigned short lds[3 * 16384 + 2 * 12288];   // 144 KiB
    unsigned short* const As = lds;                 // 3 slots x 256x64
    unsigned short* const Bs = lds + 3 * 16384;     // 2 slots x 192x64

    const int tid  = threadIdx.x;
    const int lane = tid & 63;
    const int w    = tid >> 6;   // 0..7
    const int wm   = w >> 2;     // 0..1  (128-row half)
    const int wn   = w & 3;      // 0..3  (16-col quarter of 64 h-cols)

    // Grid: 1024 = 8 kb (XCD-exclusive) x 32 bm x 4 hsub (hsub innermost).
    const int bid  = blockIdx.x;
    const int kb   = bid & 7;
    const int idx  = bid >> 3;          // 0..127
    const int bm   = (idx >> 2) * 256;
    const int hsub = idx & 3;
    const int hcb  = kb * 256 + hsub * 64;   // h-column base

    // ---- staging bases (inverse-swizzled global, linear LDS dest)
    const int srow  = tid >> 3;                 // 0..63 (row within 64-row group)
    const int chunk = (tid & 7) ^ (srow & 7);   // T2 XOR involution
    const int scol  = chunk * 8;
    const int doff  = tid * 8;                  // elem offset within an 8KB group
    const unsigned short* XbB  = Xb   + (size_t)(bm + srow) * K1 + scol;
    const unsigned short* WirB = Wirb + (size_t)(hcb + srow) * K1 + scol;
    const unsigned short* XhB  = Hbb  + (size_t)(bm + srow) * H + kb * 256 + scol;
    const unsigned short* WhB  = Whb  + (size_t)kb * 196608
                                      + (size_t)(hsub * 64 + srow) * 256 + scol;

    // ---- fragment read offsets (swizzled reads, rows are 128 B)
    const int fr  = lane & 15;
    const int k0e = (lane >> 4) * 8;
    const int mfr = (fr & 7) << 4;
    const int kb0 = ((k0e * 2) ^ mfr) >> 1;
    const int kb1 = (((k0e * 2) + 64) ^ mfr) >> 1;

    f32x4 acc[4][8] = {};   // [group][m-frag]; single 16-col n-frag per wave
    bf16x8 av[8], bv[3][2];

    // ---- prologue: queue = [B0(3), A0(4), A1(4)]
    SB1(0, 0); SA1(0, 0); SA1(1, 1);

    // ---- bodies 0..19; invariant at body t top: queue = [A(t),B(t),A(t+1)]
    KBODY(0, 0, "4", SB1(1, 1),  SA1(2, 2),  2);
    KBODY(1, 1, "4", SB1(2, 0),  SA1(3, 0),  2);
    KBODY(2, 0, "4", SB1(3, 1),  SA1(4, 1),  2);
    KBODY(0, 1, "4", SB1(4, 0),  SA1(5, 2),  2);
    KBODY(1, 0, "4", SB1(5, 1),  SA1(6, 0),  2);
    KBODY(2, 1, "4", SB1(6, 0),  SA1(7, 1),  2);
    KBODY(0, 0, "4", SB1(7, 1),  SA1(8, 2),  2);
    KBODY(1, 1, "4", SB1(8, 0),  SA1(9, 0),  2);
    KBODY(2, 0, "4", SB1(9, 1),  SA1(10, 1), 2);
    KBODY(0, 1, "4", SB1(10, 0), SA1(11, 2), 2);
    KBODY(1, 0, "4", SB1(11, 1), SA1(12, 0), 2);
    KBODY(2, 1, "4", SB1(12, 0), SA1(13, 1), 2);
    KBODY(0, 0, "4", SB1(13, 1), SA1(14, 2), 2);
    KBODY(1, 1, "4", SB1(14, 0), SA1(15, 0), 2);
    KBODY(2, 0, "4", SB1(15, 1), SA2(0, 1),  2);   // A16 -> slot 1
    KBODY(0, 1, "4", SB2(0, 0),  SA2(1, 2),  2);   // B16 -> slot 0, A17 -> 2
    KBODY(1, 0, "4", SB2(1, 1),  SA2(2, 0),  3);   // t16 (phase2 starts)
    KBODY(2, 1, "4", SB2(2, 0),  SA2(3, 1),  3);
    KBODY(0, 0, "4", SB2(3, 1),  SNOP,       3);
    KBODY(1, 1, "0", SNOP,       SNOP,       3);

    // ---- gate epilogue (h read as bf16)
    const int rq   = (lane >> 4) * 4;
    const int hcol = hcb + wn * 16 + fr;   // 0..2047
    const int lcol = hcol & 255;           // within diagonal block
    const float bir0 = b_ir_lin[hcol]        + b_ir[hcol];
    const float bir1 = b_ir_lin[2048 + hcol] + b_ir[2048 + hcol];
    const float bir2 = b_ir_lin[4096 + hcol] + b_ir[4096 + hcol];
    const float bhr0 = b_hr[kb * 768 + lcol];
    const float bhr1 = b_hr[kb * 768 + 256 + lcol];
    const float bhr2 = b_hr[kb * 768 + 512 + lcol];
    #pragma unroll
    for (int mi = 0; mi < 8; ++mi) {
        #pragma unroll
        for (int r = 0; r < 4; ++r) {
            const int row = bm + wm * 128 + mi * 16 + rq + r;
            const float pr = acc[0][mi][r] + bir0 + bhr0;
            const float pz = acc[1][mi][r] + bir1 + bhr1;
            const float xn = acc[2][mi][r] + bir2;
            const float hn = acc[3][mi][r] + bhr2;
            const float rg = sigmoidf_(pr);
            const float zg = sigmoidf_(pz);
            const float ng = tanhf_(xn + rg * hn);
            const float hv = bf2f(Hbb[(size_t)row * H + hcol]);
            out[(size_t)row * H + hcol] = (1.0f - zg) * hv + zg * ng;
        }
    }
}

// ---------------------------------------------------------------- launch
extern "C" void kernel_launch(void* const* d_in, const int* in_sizes, int n_in,
                              void* d_out, int out_size, void* d_ws, size_t ws_size,
                              hipStream_t stream) {
    const float* x        = (const float*)d_in[0];
    const float* h        = (const float*)d_in[1];
    const float* W_ir     = (const float*)d_in[2];
    const float* b_ir_lin = (const float*)d_in[3];
    const float* b_ir     = (const float*)d_in[4];
    const float* W_h      = (const float*)d_in[5];
    const float* b_hr     = (const float*)d_in[6];
    float* out = (float*)d_out;

    char* ws = (char*)d_ws;
    unsigned short* xb   = (unsigned short*)(ws);               // 16 MiB
    unsigned short* wirb = (unsigned short*)(ws + 16777216);    // 12 MiB
    unsigned short* hb   = (unsigned short*)(ws + 29360128);    // 32 MiB
    unsigned short* whb  = (unsigned short*)(ws + 62914560);    //  3 MiB

    cast_all<<<32256, 256, 0, stream>>>(x, W_ir, h, W_h, xb, wirb, hb, whb);

    gru_fused<<<1024, 512, 0, stream>>>(xb, wirb, hb, whb,
                                        b_ir_lin, b_ir, b_hr, out);
}

// Round 12
// 179.221 us; speedup vs baseline: 1.0333x; 1.0104x over previous
//
#include <hip/hip_runtime.h>
#include <cstdint>
#include <cstddef>

// Block-diagonal GRU on MI355X (gfx950), fully fused bf16 MFMA path.
// B=8192, IN=1024, H=2048, NB=8, BS=256, 3H=6144.
// Round 12: A through LDS (32 KiB, 2-slot, T2-swizzled); B operands load
// DIRECT global->register from a fragment-major image (R10 cast, verified),
// software-pipelined ONE K-TILE AHEAD (T14 issue-early): B(t+1) halves issue
// right after their registers' last use in tile t (~2000 cyc slack; WAR is
// free under in-order issue). LDS traffic per K-tile-CU drops 233KB -> 96KB,
// breaking the LDS-port wall that pinned rounds 4-11 at MfmaUtil ~40%.
// vmcnt queue at each body top: [A(t) 4 oldest, B(t) 12] -> vmcnt(12)
// retires exactly A(t); compiler inserts exact counted waits for bv uses.

typedef __attribute__((ext_vector_type(8))) short bf16x8;
typedef __attribute__((ext_vector_type(4))) float f32x4;

__device__ __forceinline__ unsigned short f2bf(float f) {
    uint32_t u = __float_as_uint(f);
    u += 0x7FFFu + ((u >> 16) & 1u);   // round-to-nearest-even
    return (unsigned short)(u >> 16);
}
__device__ __forceinline__ float bf2f(unsigned short b) {
    return __uint_as_float(((uint32_t)b) << 16);
}

__device__ __forceinline__ void gload16(const void* g, void* l) {
    __builtin_amdgcn_global_load_lds(
        (const __attribute__((address_space(1))) void*)g,
        (__attribute__((address_space(3))) void*)l,
        16, 0, 0);
}

__device__ __forceinline__ float sigmoidf_(float x) {
    return 1.0f / (1.0f + __expf(-x));
}
__device__ __forceinline__ float tanhf_(float x) {
    float e = __expf(-2.0f * fabsf(x));
    float t = (1.0f - e) / (1.0f + e);
    return copysignf(t, x);
}

// ---------------------------------------------------------------- cast
// Region map (256-thr blocks):
//  t in [0, 2097152)       : x float4 cast (linear)
//  t in [2097152, 6291456) : h float4 cast (linear)
//  t in [6291456, 7077888) : W_ir -> fragment-major bf16
//  t in [7077888, 7274496) : W_h  -> fragment-major bf16
// W_ir frag unit u: lane=u&63, fi=u>>6, kblk=fi&31, rb=fi>>5;
//   reads W_ir[rb*16 + (lane&15)][kblk*32 + (lane>>4)*8 .. +8].
// W_h frag unit u2: lane=u2&63, fi=u2>>6, kb=fi/384, rem=fi%384
//   (rb2=rem>>3, kblk2=rem&7); reads W_h[kb][rb2*16+(lane&15)][kblk2*32+...].
__global__ __launch_bounds__(256)
void cast_all(const float* __restrict__ x, const float* __restrict__ wir,
              const float* __restrict__ h, const float* __restrict__ wh,
              unsigned short* __restrict__ xb, unsigned short* __restrict__ wirF,
              unsigned short* __restrict__ hb, unsigned short* __restrict__ whF) {
    const int t = blockIdx.x * 256 + threadIdx.x;
    if (t < 6291456) {   // linear casts
        const float* s; unsigned short* d; int j;
        if (t < 2097152) { s = x; d = xb; j = t; }
        else             { s = h; d = hb; j = t - 2097152; }
        const float4 v = *reinterpret_cast<const float4*>(s + (size_t)j * 4);
        ushort4 o;
        o.x = f2bf(v.x); o.y = f2bf(v.y); o.z = f2bf(v.z); o.w = f2bf(v.w);
        *reinterpret_cast<ushort4*>(d + (size_t)j * 4) = o;
        return;
    }
    const float* src; unsigned short* dst; size_t in_off; int u;
    if (t < 7077888) {   // W_ir fragments
        u = t - 6291456;
        const int lane = u & 63, fi = u >> 6;
        const int kblk = fi & 31, rb = fi >> 5;
        in_off = (size_t)(rb * 16 + (lane & 15)) * 1024 + kblk * 32 + (lane >> 4) * 8;
        src = wir; dst = wirF;
    } else {             // W_h fragments
        u = t - 7077888;
        const int lane = u & 63, fi = u >> 6;
        const int kb = fi / 384, rem = fi - kb * 384;
        const int rb2 = rem >> 3, kblk2 = rem & 7;
        in_off = (size_t)kb * 196608
               + (size_t)(rb2 * 16 + (lane & 15)) * 256 + kblk2 * 32 + (lane >> 4) * 8;
        src = wh; dst = whF;
    }
    const float4 v0 = *reinterpret_cast<const float4*>(src + in_off);
    const float4 v1 = *reinterpret_cast<const float4*>(src + in_off + 4);
    bf16x8 o;
    o[0] = (short)f2bf(v0.x); o[1] = (short)f2bf(v0.y);
    o[2] = (short)f2bf(v0.z); o[3] = (short)f2bf(v0.w);
    o[4] = (short)f2bf(v1.x); o[5] = (short)f2bf(v1.y);
    o[6] = (short)f2bf(v1.z); o[7] = (short)f2bf(v1.w);
    *reinterpret_cast<bf16x8*>(dst + (size_t)u * 8) = o;
}

// ---------------------------------------------------------------- fused GRU
// 256 thr (4 waves 2Mx2N), BM=128, 64 h-cols, 3 strips, BK=64, 20 K-tiles.
// acc[4][4][2]: groups 0=r(sum), 1=z(sum), 2=wxn, 3=whn; [m-frag][n-frag].
// NT = 2 (phase1: x @ W_ir^T) / 3 (phase2: hb @ W_h[kb]^T).

#define MFMA_(a_, b_, c_) __builtin_amdgcn_mfma_f32_16x16x32_bf16(a_, b_, c_, 0, 0, 0)

#define MM24H(KH, NT) do {                                                     \
    _Pragma("unroll")                                                          \
    for (int m_ = 0; m_ < 4; ++m_) {                                           \
        acc[0][m_][0]  = MFMA_(av[m_], bv[0][0][KH], acc[0][m_][0]);           \
        acc[0][m_][1]  = MFMA_(av[m_], bv[0][1][KH], acc[0][m_][1]);           \
        acc[1][m_][0]  = MFMA_(av[m_], bv[1][0][KH], acc[1][m_][0]);           \
        acc[1][m_][1]  = MFMA_(av[m_], bv[1][1][KH], acc[1][m_][1]);           \
        acc[NT][m_][0] = MFMA_(av[m_], bv[2][0][KH], acc[NT][m_][0]);          \
        acc[NT][m_][1] = MFMA_(av[m_], bv[2][1][KH], acc[NT][m_][1]);          \
    }                                                                          \
} while (0)

// B fragment loads (direct global->reg, frag-major image).
// phase1: frag offset ((s*128 + rbB1 + n)*32 + kt*2 + kh) * 512 + lane*8
#define BL1H(kt, kh) do {                                                      \
    _Pragma("unroll") for (int s_ = 0; s_ < 3; ++s_)                           \
    _Pragma("unroll") for (int n_ = 0; n_ < 2; ++n_)                           \
        bv[s_][n_][kh] = *(const bf16x8*)(WirF +                               \
            (((size_t)(s_ * 128 + rbB1 + n_) * 32 + (kt) * 2 + (kh)) << 9) + l8); \
} while (0)
// phase2: base kb*196608 + ((s*16 + rbB2 + n)*8 + k2*2 + kh) * 512 + lane*8
#define BL2H(k2, kh) do {                                                      \
    _Pragma("unroll") for (int s_ = 0; s_ < 3; ++s_)                           \
    _Pragma("unroll") for (int n_ = 0; n_ < 2; ++n_)                           \
        bv[s_][n_][kh] = *(const bf16x8*)(WhF + whbase +                       \
            (((size_t)(s_ * 16 + rbB2 + n_) * 8 + (k2) * 2 + (kh)) << 9) + l8); \
} while (0)
#define BNOP ((void)0)

// A staging (4 x gload16; inverse-swizzled source, linear LDS dest, T2/G21)
#define I_A1(kt, ds) do {                                                      \
    gload16(XbB + 0 * 32768 + (kt) * 64, As + (ds) * 8192 + 0 * 2048 + doff);  \
    gload16(XbB + 1 * 32768 + (kt) * 64, As + (ds) * 8192 + 1 * 2048 + doff);  \
    gload16(XbB + 2 * 32768 + (kt) * 64, As + (ds) * 8192 + 2 * 2048 + doff);  \
    gload16(XbB + 3 * 32768 + (kt) * 64, As + (ds) * 8192 + 3 * 2048 + doff); } while (0)
#define I_A2(k2, ds) do {                                                      \
    gload16(XhB + 0 * 65536 + (k2) * 64, As + (ds) * 8192 + 0 * 2048 + doff);  \
    gload16(XhB + 1 * 65536 + (k2) * 64, As + (ds) * 8192 + 1 * 2048 + doff);  \
    gload16(XhB + 2 * 65536 + (k2) * 64, As + (ds) * 8192 + 2 * 2048 + doff);  \
    gload16(XhB + 3 * 65536 + (k2) * 64, As + (ds) * 8192 + 3 * 2048 + doff); } while (0)
#define ANOP ((void)0)

// Body for K-tile t (slot sl = t&1), steady state:
//  vmcnt(12): retires A(t) DMAs (oldest 4); B(t) waits are compiler-counted.
//  barrier: A(t) visible; slot sl^1 readers (body t-1) done.
//  stage A(t+1) -> sl^1 ; read av kb0 ; MFMA kh0 (bv loaded last body) ;
//  issue B(t+1) kh0 (regs just consumed; WAR free) ; read av kb1 ;
//  MFMA kh1 ; issue B(t+1) kh1.
#define BODY(sl, AST, BH0, BH1, NT) do {                                       \
    asm volatile("s_waitcnt vmcnt(12)" ::: "memory");                          \
    __builtin_amdgcn_s_barrier();                                              \
    AST;                                                                       \
    const unsigned short* aS = As + (sl) * 8192;                               \
    _Pragma("unroll") for (int m_ = 0; m_ < 4; ++m_)                           \
        av[m_] = *(const bf16x8*)(aS + (wm * 64 + m_ * 16 + fr) * 64 + kb0);   \
    MM24H(0, NT);                                                              \
    BH0;                                                                       \
    _Pragma("unroll") for (int m_ = 0; m_ < 4; ++m_)                           \
        av[m_] = *(const bf16x8*)(aS + (wm * 64 + m_ * 16 + fr) * 64 + kb1);   \
    MM24H(1, NT);                                                              \
    BH1;                                                                       \
} while (0)

__global__ __launch_bounds__(256, 2)
void gru_fused(const unsigned short* __restrict__ Xb,    // [8192][1024] bf16
               const unsigned short* __restrict__ WirF,  // frag-major W_ir bf16
               const unsigned short* __restrict__ Hbb,   // [8192][2048] bf16
               const unsigned short* __restrict__ WhF,   // frag-major W_h bf16
               const float* __restrict__ b_ir_lin,       // [6144]
               const float* __restrict__ b_ir,           // [6144]
               const float* __restrict__ b_hr,           // [6144]
               float* __restrict__ out) {                // [8192][2048] f32
    constexpr int K1 = 1024, H = 2048;
    __shared__ unsigned short lds[2 * 8192];   // 32 KiB, A only
    unsigned short* const As = lds;

    const int tid  = threadIdx.x;
    const int lane = tid & 63;
    const int w    = tid >> 6;   // 0..3
    const int wm   = w >> 1;     // 0..1 (64-row half)
    const int wn   = w & 1;      // 0..1 (32-col half)

    // Grid: 2048 = 8 kb (XCD-exclusive) x 64 bm x 4 hsub (hsub innermost).
    const int bid  = blockIdx.x;
    const int kb   = bid & 7;
    const int idx  = bid >> 3;
    const int bm   = (idx >> 2) * 128;
    const int hsub = idx & 3;
    const int hcb  = kb * 256 + hsub * 64;   // h-column base

    // ---- A staging bases (inverse-swizzled global, linear LDS dest)
    const int srow  = tid >> 3;                 // 0..31 (row within 32-row chunk)
    const int chunk = (tid & 7) ^ (srow & 7);   // T2 XOR involution
    const int scol  = chunk * 8;
    const int doff  = tid * 8;
    const unsigned short* XbB = Xb  + (size_t)(bm + srow) * K1 + scol;
    const unsigned short* XhB = Hbb + (size_t)(bm + srow) * H + kb * 256 + scol;

    // ---- A fragment read offsets (swizzled, rows 128 B)
    const int fr  = lane & 15;
    const int k0e = (lane >> 4) * 8;
    const int mfr = (fr & 7) << 4;
    const int kb0 = ((k0e * 2) ^ mfr) >> 1;
    const int kb1 = (((k0e * 2) + 64) ^ mfr) >> 1;

    // ---- B fragment addressing (direct global, frag-major image)
    const int l8   = lane * 8;
    const int rbB1 = kb * 16 + hsub * 4 + wn * 2;   // + s*128 + n
    const int rbB2 = hsub * 4 + wn * 2;             // + s*16 + n
    const size_t whbase = (size_t)kb * 196608;

    f32x4 acc[4][4][2] = {};   // [group][m-frag][n-frag]
    bf16x8 av[4], bv[3][2][2];

    // ---- prologue: A(0) DMAs first (oldest in queue), then B(0) 12 loads
    I_A1(0, 0);
    BL1H(0, 0); BL1H(0, 1);
    // queue: [A(0) 4, B(0) 12] -> body 0's vmcnt(12) retires A(0), same as
    // steady state. bv waits handled by compiler-counted vmcnt at first use.

    // ---- phase1: tiles 0..14
    BODY(0, I_A1(1, 1),  BL1H(1, 0),  BL1H(1, 1),  2);
    BODY(1, I_A1(2, 0),  BL1H(2, 0),  BL1H(2, 1),  2);
    BODY(0, I_A1(3, 1),  BL1H(3, 0),  BL1H(3, 1),  2);
    BODY(1, I_A1(4, 0),  BL1H(4, 0),  BL1H(4, 1),  2);
    BODY(0, I_A1(5, 1),  BL1H(5, 0),  BL1H(5, 1),  2);
    BODY(1, I_A1(6, 0),  BL1H(6, 0),  BL1H(6, 1),  2);
    BODY(0, I_A1(7, 1),  BL1H(7, 0),  BL1H(7, 1),  2);
    BODY(1, I_A1(8, 0),  BL1H(8, 0),  BL1H(8, 1),  2);
    BODY(0, I_A1(9, 1),  BL1H(9, 0),  BL1H(9, 1),  2);
    BODY(1, I_A1(10, 0), BL1H(10, 0), BL1H(10, 1), 2);
    BODY(0, I_A1(11, 1), BL1H(11, 0), BL1H(11, 1), 2);
    BODY(1, I_A1(12, 0), BL1H(12, 0), BL1H(12, 1), 2);
    BODY(0, I_A1(13, 1), BL1H(13, 0), BL1H(13, 1), 2);
    BODY(1, I_A1(14, 0), BL1H(14, 0), BL1H(14, 1), 2);
    BODY(0, I_A1(15, 1), BL1H(15, 0), BL1H(15, 1), 2);
    // ---- tile 15 (last phase1): stage/issue tile 16 (phase2)
    BODY(1, I_A2(0, 0),  BL2H(0, 0),  BL2H(0, 1),  2);
    // ---- phase2: tiles 16..19
    BODY(0, I_A2(1, 1),  BL2H(1, 0),  BL2H(1, 1),  3);
    BODY(1, I_A2(2, 0),  BL2H(2, 0),  BL2H(2, 1),  3);
    BODY(0, I_A2(3, 1),  BL2H(3, 0),  BL2H(3, 1),  3);
    BODY(1, ANOP,        BNOP,        BNOP,        3);

    // ---- gate epilogue (h read as bf16)
    const int rq = (lane >> 4) * 4;
    #pragma unroll
    for (int n = 0; n < 2; ++n) {
        const int hcol = hcb + wn * 32 + n * 16 + fr;   // 0..2047
        const int lcol = hcol & 255;                    // within diagonal block
        const float bir0 = b_ir_lin[hcol]        + b_ir[hcol];
        const float bir1 = b_ir_lin[2048 + hcol] + b_ir[2048 + hcol];
        const float bir2 = b_ir_lin[4096 + hcol] + b_ir[4096 + hcol];
        const float bhr0 = b_hr[kb * 768 + lcol];
        const float bhr1 = b_hr[kb * 768 + 256 + lcol];
        const float bhr2 = b_hr[kb * 768 + 512 + lcol];
        #pragma unroll
        for (int mi = 0; mi < 4; ++mi) {
            #pragma unroll
            for (int r = 0; r < 4; ++r) {
                const int row = bm + wm * 64 + mi * 16 + rq + r;
                const float pr = acc[0][mi][n][r] + bir0 + bhr0;
                const float pz = acc[1][mi][n][r] + bir1 + bhr1;
                const float xn = acc[2][mi][n][r] + bir2;
                const float hn = acc[3][mi][n][r] + bhr2;
                const float rg = sigmoidf_(pr);
                const float zg = sigmoidf_(pz);
                const float ng = tanhf_(xn + rg * hn);
                const float hv = bf2f(Hbb[(size_t)row * H + hcol]);
                out[(size_t)row * H + hcol] = (1.0f - zg) * hv + zg * ng;
            }
        }
    }
}

// ---------------------------------------------------------------- launch
extern "C" void kernel_launch(void* const* d_in, const int* in_sizes, int n_in,
                              void* d_out, int out_size, void* d_ws, size_t ws_size,
                              hipStream_t stream) {
    const float* x        = (const float*)d_in[0];
    const float* h        = (const float*)d_in[1];
    const float* W_ir     = (const float*)d_in[2];
    const float* b_ir_lin = (const float*)d_in[3];
    const float* b_ir     = (const float*)d_in[4];
    const float* W_h      = (const float*)d_in[5];
    const float* b_hr     = (const float*)d_in[6];
    float* out = (float*)d_out;

    char* ws = (char*)d_ws;
    unsigned short* xb   = (unsigned short*)(ws);               // 16 MiB
    unsigned short* wirF = (unsigned short*)(ws + 16777216);    // 12 MiB (frag-major)
    unsigned short* hb   = (unsigned short*)(ws + 29360128);    // 32 MiB
    unsigned short* whF  = (unsigned short*)(ws + 62914560);    //  3 MiB (frag-major)

    cast_all<<<28416, 256, 0, stream>>>(x, W_ir, h, W_h, xb, wirF, hb, whF);

    gru_fused<<<2048, 256, 0, stream>>>(xb, wirF, hb, whF,
                                        b_ir_lin, b_ir, b_hr, out);
}

// Round 13
// 170.642 us; speedup vs baseline: 1.0853x; 1.0503x over previous
//
#include <hip/hip_runtime.h>
#include <cstdint>
#include <cstddef>

// Block-diagonal GRU on MI355X (gfx950), fully fused bf16 MFMA path.
// B=8192, IN=1024, H=2048, NB=8, BS=256, 3H=6144.
// One kernel computes wx (K=1024) AND wh (K=256, block-diagonal) for a
// 128x64 h-column tile, then applies the GRU gates in the epilogue.
// Geometry: 256 thr (4 waves 2Mx2N), BM=128, BK=64, LDS 80 KiB -> 2 blocks/CU.
// Round 13: m201 phase ordering — ds_reads issue BEFORE the phase barrier
// (barrier-wait covers LDS latency; lgkmcnt(0) after it is ~free), then
// sched_barrier(0) (rule #18) + setprio(1) around each 12-MFMA cluster.
// 4 phases/K-tile, 5 barriers total (same count as R7, safer placement),
// one counted vmcnt(4)/K-tile (never 0 until the peel).

typedef __attribute__((ext_vector_type(8))) short bf16x8;
typedef __attribute__((ext_vector_type(4))) float f32x4;

__device__ __forceinline__ unsigned short f2bf(float f) {
    uint32_t u = __float_as_uint(f);
    u += 0x7FFFu + ((u >> 16) & 1u);   // round-to-nearest-even
    return (unsigned short)(u >> 16);
}
__device__ __forceinline__ float bf2f(unsigned short b) {
    return __uint_as_float(((uint32_t)b) << 16);
}

__device__ __forceinline__ void gload16(const void* g, void* l) {
    __builtin_amdgcn_global_load_lds(
        (const __attribute__((address_space(1))) void*)g,
        (__attribute__((address_space(3))) void*)l,
        16, 0, 0);
}

__device__ __forceinline__ float sigmoidf_(float x) {
    return 1.0f / (1.0f + __expf(-x));
}
__device__ __forceinline__ float tanhf_(float x) {
    float e = __expf(-2.0f * fabsf(x));
    float t = (1.0f - e) / (1.0f + e);
    return copysignf(t, x);
}

// ---------------------------------------------------------------- one cast
// regions (in float4 units): x 2097152 | W_ir 1572864 | h 4194304 | W_h 393216
__global__ __launch_bounds__(256)
void cast_all(const float* __restrict__ x, const float* __restrict__ wir,
              const float* __restrict__ h, const float* __restrict__ wh,
              unsigned short* __restrict__ xb, unsigned short* __restrict__ wirb,
              unsigned short* __restrict__ hb, unsigned short* __restrict__ whb) {
    const int i = blockIdx.x * 256 + threadIdx.x;
    const float* s; unsigned short* d; int j;
    if (i < 2097152)      { s = x;   d = xb;   j = i; }
    else if (i < 3670016) { s = wir; d = wirb; j = i - 2097152; }
    else if (i < 7864320) { s = h;   d = hb;   j = i - 3670016; }
    else                  { s = wh;  d = whb;  j = i - 7864320; }
    const float4 v = *reinterpret_cast<const float4*>(s + (size_t)j * 4);
    ushort4 o;
    o.x = f2bf(v.x); o.y = f2bf(v.y); o.z = f2bf(v.z); o.w = f2bf(v.w);
    *reinterpret_cast<ushort4*>(d + (size_t)j * 4) = o;
}

// ---------------------------------------------------------------- fused GRU
// acc groups: 0=r(sum of both GEMMs), 1=z(sum), 2=wxn, 3=whn.
// NT = 2 during phase1 (x @ W_ir^T), 3 during phase2 (hb @ W_h[kb]^T).
// A tile 128x64 (4 chunks of 32 rows), B tile 192x64 (6 chunks).
// Staging issues/thread/K-tile: 10 = [B0..B3] + [B4,B5,A0,A1] + [A2,A3].
// LDS rows 128 B, T2 XOR-swizzle byte^=(row&7)<<4 via inverse-swizzled
// global source (linear gload_lds dest) + swizzled ds_read (G21).

#define MM12(mb, NT) do {                                                      \
    asm volatile("s_waitcnt lgkmcnt(0)" ::: "memory");                         \
    __builtin_amdgcn_sched_barrier(0);                                         \
    __builtin_amdgcn_s_setprio(1);                                             \
    _Pragma("unroll")                                                          \
    for (int m_ = 0; m_ < 2; ++m_) {                                           \
        acc[0][(mb) + m_][0] = __builtin_amdgcn_mfma_f32_16x16x32_bf16(        \
            av[m_], bv[0][0], acc[0][(mb) + m_][0], 0, 0, 0);                  \
        acc[0][(mb) + m_][1] = __builtin_amdgcn_mfma_f32_16x16x32_bf16(        \
            av[m_], bv[0][1], acc[0][(mb) + m_][1], 0, 0, 0);                  \
        acc[1][(mb) + m_][0] = __builtin_amdgcn_mfma_f32_16x16x32_bf16(        \
            av[m_], bv[1][0], acc[1][(mb) + m_][0], 0, 0, 0);                  \
        acc[1][(mb) + m_][1] = __builtin_amdgcn_mfma_f32_16x16x32_bf16(        \
            av[m_], bv[1][1], acc[1][(mb) + m_][1], 0, 0, 0);                  \
        acc[NT][(mb) + m_][0] = __builtin_amdgcn_mfma_f32_16x16x32_bf16(       \
            av[m_], bv[2][0], acc[NT][(mb) + m_][0], 0, 0, 0);                 \
        acc[NT][(mb) + m_][1] = __builtin_amdgcn_mfma_f32_16x16x32_bf16(       \
            av[m_], bv[2][1], acc[NT][(mb) + m_][1], 0, 0, 0);                 \
    }                                                                          \
    __builtin_amdgcn_s_setprio(0);                                             \
} while (0)

#define RDAV(mb, kb_) do {                                                     \
    av[0] = *(const bf16x8*)(aS + (wm * 64 + ((mb) + 0) * 16 + fr) * 64 + (kb_)); \
    av[1] = *(const bf16x8*)(aS + (wm * 64 + ((mb) + 1) * 16 + fr) * 64 + (kb_)); \
} while (0)
#define RDBV(kb_) do {                                                         \
    _Pragma("unroll")                                                          \
    for (int s_ = 0; s_ < 3; ++s_) {                                           \
        bv[s_][0] = *(const bf16x8*)(bS + ((s_) * 64 + wn * 32 + 0 * 16 + fr) * 64 + (kb_)); \
        bv[s_][1] = *(const bf16x8*)(bS + ((s_) * 64 + wn * 32 + 1 * 16 + fr) * 64 + (kb_)); \
    }                                                                          \
} while (0)

// phase1 staging groups (kt in units of 64 elements along K=1024)
#define I0_1(kt, ds) do {                                                      \
    gload16(b1[0] + (size_t)(kt) * 64, Bs + (ds) * 12288 + 0 * 2048 + doff);   \
    gload16(b1[1] + (size_t)(kt) * 64, Bs + (ds) * 12288 + 1 * 2048 + doff);   \
    gload16(b1[2] + (size_t)(kt) * 64, Bs + (ds) * 12288 + 2 * 2048 + doff);   \
    gload16(b1[3] + (size_t)(kt) * 64, Bs + (ds) * 12288 + 3 * 2048 + doff); } while (0)
#define I1_1(kt, ds) do {                                                      \
    gload16(b1[4] + (size_t)(kt) * 64, Bs + (ds) * 12288 + 4 * 2048 + doff);   \
    gload16(b1[5] + (size_t)(kt) * 64, Bs + (ds) * 12288 + 5 * 2048 + doff);   \
    gload16(a1[0] + (size_t)(kt) * 64, As + (ds) * 8192 + 0 * 2048 + doff);    \
    gload16(a1[1] + (size_t)(kt) * 64, As + (ds) * 8192 + 1 * 2048 + doff); } while (0)
#define I2_1(kt, ds) do {                                                      \
    gload16(a1[2] + (size_t)(kt) * 64, As + (ds) * 8192 + 2 * 2048 + doff);    \
    gload16(a1[3] + (size_t)(kt) * 64, As + (ds) * 8192 + 3 * 2048 + doff); } while (0)
// phase2 staging groups (k2 in units of 64 along K=256)
#define I0_2(k2, ds) do {                                                      \
    gload16(b2[0] + (size_t)(k2) * 64, Bs + (ds) * 12288 + 0 * 2048 + doff);   \
    gload16(b2[1] + (size_t)(k2) * 64, Bs + (ds) * 12288 + 1 * 2048 + doff);   \
    gload16(b2[2] + (size_t)(k2) * 64, Bs + (ds) * 12288 + 2 * 2048 + doff);   \
    gload16(b2[3] + (size_t)(k2) * 64, Bs + (ds) * 12288 + 3 * 2048 + doff); } while (0)
#define I1_2(k2, ds) do {                                                      \
    gload16(b2[4] + (size_t)(k2) * 64, Bs + (ds) * 12288 + 4 * 2048 + doff);   \
    gload16(b2[5] + (size_t)(k2) * 64, Bs + (ds) * 12288 + 5 * 2048 + doff);   \
    gload16(a2[0] + (size_t)(k2) * 64, As + (ds) * 8192 + 0 * 2048 + doff);    \
    gload16(a2[1] + (size_t)(k2) * 64, As + (ds) * 8192 + 1 * 2048 + doff); } while (0)
#define I2_2(k2, ds) do {                                                      \
    gload16(a2[2] + (size_t)(k2) * 64, As + (ds) * 8192 + 2 * 2048 + doff);    \
    gload16(a2[3] + (size_t)(k2) * 64, As + (ds) * 8192 + 3 * 2048 + doff); } while (0)

// One K-tile (slot sl). Phase pattern: reads -> barrier -> lgkm0 -> MFMA.
//  top: I0(t+1); vmcnt(W0) [tile t fully landed]; barrier;
//  P0: RDBV kb0 + RDAV m01 kb0 | bar | 12 MFMA
//  P1: RDAV m23 kb0, I1(t+1)   | bar | 12 MFMA
//  P2: RDBV kb1 + RDAV m01 kb1, I2(t+1) | bar | 12 MFMA
//  P3: RDAV m23 kb1            | bar | 12 MFMA
// Slot safety: I0(t+1) writes slot sl^1, whose last readers (tile t-1) all
// precede tile t-1's P3 barrier < this issue. 5 barriers/K-tile.
#define KSTEP(slot_, I0, W0, I1, I2, NT) do {                                  \
    const unsigned short* aS = As + (slot_) * 8192;                            \
    const unsigned short* bS = Bs + (slot_) * 12288;                           \
    I0;                                                                        \
    asm volatile("s_waitcnt vmcnt(" W0 ")" ::: "memory");                      \
    __builtin_amdgcn_s_barrier();                                              \
    RDBV(kb0); RDAV(0, kb0);                                                   \
    __builtin_amdgcn_s_barrier();                                              \
    MM12(0, NT);                                                               \
    RDAV(2, kb0);                                                              \
    I1;                                                                        \
    __builtin_amdgcn_s_barrier();                                              \
    MM12(2, NT);                                                               \
    RDBV(kb1); RDAV(0, kb1);                                                   \
    I2;                                                                        \
    __builtin_amdgcn_s_barrier();                                              \
    MM12(0, NT);                                                               \
    RDAV(2, kb1);                                                              \
    __builtin_amdgcn_s_barrier();                                              \
    MM12(2, NT);                                                               \
} while (0)

__global__ __launch_bounds__(256, 2)
void gru_fused(const unsigned short* __restrict__ Xb,    // [8192][1024] bf16
               const unsigned short* __restrict__ Wirb,  // [6144][1024] bf16
               const unsigned short* __restrict__ Hbb,   // [8192][2048] bf16
               const unsigned short* __restrict__ Whb,   // [8][768][256] bf16
               const float* __restrict__ b_ir_lin,       // [6144]
               const float* __restrict__ b_ir,           // [6144]
               const float* __restrict__ b_hr,           // [6144]
               float* __restrict__ out) {                // [8192][2048] f32
    constexpr int K1 = 1024, H = 2048;
    __shared__ unsigned short lds[2 * 8192 + 2 * 12288];   // 80 KiB
    unsigned short* const As = lds;
    unsigned short* const Bs = lds + 2 * 8192;

    const int tid  = threadIdx.x;
    const int lane = tid & 63;
    const int w    = tid >> 6;   // 0..3
    const int wm   = w >> 1;     // 0..1 (64-row half)
    const int wn   = w & 1;      // 0..1 (32-col half)

    // Grid: 2048 = 8 kb (XCD-exclusive) x 64 bm x 4 hsub (hsub innermost).
    const int bid  = blockIdx.x;
    const int kb   = bid & 7;
    const int idx  = bid >> 3;          // 0..255
    const int bm   = (idx >> 2) * 128;
    const int hsub = idx & 3;
    const int hcb  = kb * 256 + hsub * 64;   // h-column base

    // ---- staging sources (inverse-swizzled global, linear LDS dest)
    const int srow  = tid >> 3;                 // 0..31 (row within 32-row chunk)
    const int chunk = (tid & 7) ^ (srow & 7);   // T2 XOR involution
    const int scol  = chunk * 8;
    const int doff  = tid * 8;                  // element offset within a chunk
    const unsigned short* a1[4];
    const unsigned short* a2[4];
    #pragma unroll
    for (int q = 0; q < 4; ++q) {
        a1[q] = Xb  + (size_t)(bm + q * 32 + srow) * K1 + scol;
        a2[q] = Hbb + (size_t)(bm + q * 32 + srow) * H + kb * 256 + scol;
    }
    const unsigned short* b1[6];
    const unsigned short* b2[6];
    #pragma unroll
    for (int q = 0; q < 6; ++q) {
        const int s  = q >> 1;
        const int rr = (q & 1) * 32 + srow;
        b1[q] = Wirb + (size_t)(s * 2048 + hcb + rr) * K1 + scol;
        b2[q] = Whb + (size_t)kb * 196608 + (size_t)(s * 256 + hsub * 64 + rr) * 256 + scol;
    }

    // ---- fragment read offsets (swizzled reads, rows are 128 B)
    const int fr  = lane & 15;
    const int k0e = (lane >> 4) * 8;
    const int mfr = (fr & 7) << 4;
    const int kb0 = ((k0e * 2) ^ mfr) >> 1;
    const int kb1 = (((k0e * 2) + 64) ^ mfr) >> 1;

    f32x4 acc[4][4][2] = {};   // [group][m-frag][n-frag]
    bf16x8 av[2], bv[3][2];

    // ---- prologue: stage tile 0 (phase1)
    I0_1(0, 0); I1_1(0, 0); I2_1(0, 0);

    // ---- phase1: tiles 0..14 (stage t+1, phase1)
    #pragma unroll 1
    for (int t = 0; t < 15; ++t) {
        const int sl = t & 1, nx = sl ^ 1;
        KSTEP(sl, I0_1(t + 1, nx), "4", I1_1(t + 1, nx), I2_1(t + 1, nx), 2);
    }
    // ---- bridge: compute tile 15 (phase1), stage tile 16 (phase2, k2=0)
    KSTEP(1, I0_2(0, 0), "4", I1_2(0, 0), I2_2(0, 0), 2);
    // ---- phase2: tiles 16..18 (stage k2 = t-15)
    #pragma unroll 1
    for (int t = 16; t < 19; ++t) {
        const int sl = t & 1, nx = sl ^ 1;
        KSTEP(sl, I0_2(t - 15, nx), "4", I1_2(t - 15, nx), I2_2(t - 15, nx), 3);
    }
    // ---- peel: tile 19, drain
    KSTEP(1, ((void)0), "0", ((void)0), ((void)0), 3);

    // ---- gate epilogue (h read as bf16)
    const int rq = (lane >> 4) * 4;
    #pragma unroll
    for (int n = 0; n < 2; ++n) {
        const int hcol = hcb + wn * 32 + n * 16 + fr;   // 0..2047
        const int lcol = hcol & 255;                    // within diagonal block
        const float bir0 = b_ir_lin[hcol]        + b_ir[hcol];
        const float bir1 = b_ir_lin[2048 + hcol] + b_ir[2048 + hcol];
        const float bir2 = b_ir_lin[4096 + hcol] + b_ir[4096 + hcol];
        const float bhr0 = b_hr[kb * 768 + lcol];
        const float bhr1 = b_hr[kb * 768 + 256 + lcol];
        const float bhr2 = b_hr[kb * 768 + 512 + lcol];
        #pragma unroll
        for (int mi = 0; mi < 4; ++mi) {
            #pragma unroll
            for (int r = 0; r < 4; ++r) {
                const int row = bm + wm * 64 + mi * 16 + rq + r;
                const float pr = acc[0][mi][n][r] + bir0 + bhr0;
                const float pz = acc[1][mi][n][r] + bir1 + bhr1;
                const float xn = acc[2][mi][n][r] + bir2;
                const float hn = acc[3][mi][n][r] + bhr2;
                const float rg = sigmoidf_(pr);
                const float zg = sigmoidf_(pz);
                const float ng = tanhf_(xn + rg * hn);
                const float hv = bf2f(Hbb[(size_t)row * H + hcol]);
                out[(size_t)row * H + hcol] = (1.0f - zg) * hv + zg * ng;
            }
        }
    }
}

// ---------------------------------------------------------------- launch
extern "C" void kernel_launch(void* const* d_in, const int* in_sizes, int n_in,
                              void* d_out, int out_size, void* d_ws, size_t ws_size,
                              hipStream_t stream) {
    const float* x        = (const float*)d_in[0];
    const float* h        = (const float*)d_in[1];
    const float* W_ir     = (const float*)d_in[2];
    const float* b_ir_lin = (const float*)d_in[3];
    const float* b_ir     = (const float*)d_in[4];
    const float* W_h      = (const float*)d_in[5];
    const float* b_hr     = (const float*)d_in[6];
    float* out = (float*)d_out;

    char* ws = (char*)d_ws;
    unsigned short* xb   = (unsigned short*)(ws);               // 16 MiB
    unsigned short* wirb = (unsigned short*)(ws + 16777216);    // 12 MiB
    unsigned short* hb   = (unsigned short*)(ws + 29360128);    // 32 MiB
    unsigned short* whb  = (unsigned short*)(ws + 62914560);    //  3 MiB

    cast_all<<<32256, 256, 0, stream>>>(x, W_ir, h, W_h, xb, wirb, hb, whb);

    gru_fused<<<2048, 256, 0, stream>>>(xb, wirb, hb, whb,
                                        b_ir_lin, b_ir, b_hr, out);
}